// Round 8
// baseline (819.432 us; speedup 1.0000x reference)
//
#include <hip/hip_runtime.h>
#include <hip/hip_bf16.h>
#include <math.h>
#include <stdint.h>

typedef unsigned short u16;
typedef __attribute__((ext_vector_type(8))) short bf8;    // 8 bf16 raw bits (4 VGPRs)
typedef __attribute__((ext_vector_type(4))) float f4;     // 16x16 MFMA C/D frag
typedef __attribute__((ext_vector_type(16))) float f16v;  // 32x32 MFMA C/D frag

#define SC_LOG2E 0.09016844f   // 256^-0.5 * log2(e)

__device__ __forceinline__ float b2f(u16 u) {
    union { uint32_t i; float f; } v; v.i = ((uint32_t)u) << 16; return v.f;
}
__device__ __forceinline__ u16 f2b(float f) {
    union { float f; uint32_t i; } v; v.f = f;
    uint32_t r = (v.i + 0x7FFFu + ((v.i >> 16) & 1u)) >> 16;
    return (u16)r;
}

// ---------------------------------------------------------------------------
// Kernel 0: weight prep (f32 -> bf16, transposed).
// ---------------------------------------------------------------------------
__global__ __launch_bounds__(256) void prep_weights(
        const float* __restrict__ Wqkv, const float* __restrict__ Wgate,
        const float* __restrict__ Wproj,
        u16* __restrict__ WT_all, u16* __restrict__ WTp) {
    int e = blockIdx.x * 256 + threadIdx.x;
    if (e < 262144) {
        int n = e >> 8, k = e & 255;
        WT_all[e] = f2b((n < 768) ? Wqkv[k * 768 + n] : Wgate[k * 256 + (n - 768)]);
    } else {
        int e2 = e - 262144;
        int n = e2 >> 8, k = e2 & 255;
        WTp[e2] = f2b(Wproj[k * 256 + n]);
    }
}

// ---------------------------------------------------------------------------
// Kernel 1: fused GEMM  y = x @ [W_qkv | W_gate]  (M=16384, N=1024, K=256)
// ---------------------------------------------------------------------------
__global__ __launch_bounds__(512) void gemm_qkvz(
        const float* __restrict__ x, const u16* __restrict__ WT,
        const float* __restrict__ b_gate,
        u16* __restrict__ qo, u16* __restrict__ ko,
        u16* __restrict__ vT, u16* __restrict__ zo) {
    __shared__ u16 As[128][72];
    __shared__ u16 Bs[256][72];
    const int t = threadIdx.x;
    const int w = t >> 6, lane = t & 63, l15 = lane & 15, q4 = lane >> 4;
    const int m0 = blockIdx.x * 128;
    const int n0 = blockIdx.y * 256;

    f4 acc[16];
#pragma unroll
    for (int i = 0; i < 16; i++) acc[i] = (f4){0.f, 0.f, 0.f, 0.f};

    for (int kt = 0; kt < 4; ++kt) {
        __syncthreads();
#pragma unroll
        for (int p = 0; p < 2; p++) {   // A tile: 128x64, f32 -> bf16
            int r = p * 64 + (t >> 3), cg = (t & 7) * 8;
            const float* xs = &x[(m0 + r) * 256 + kt * 64 + cg];
            float4 f0 = *(const float4*)xs;
            float4 f1 = *(const float4*)(xs + 4);
            u16 tmp[8];
            tmp[0] = f2b(f0.x); tmp[1] = f2b(f0.y);
            tmp[2] = f2b(f0.z); tmp[3] = f2b(f0.w);
            tmp[4] = f2b(f1.x); tmp[5] = f2b(f1.y);
            tmp[6] = f2b(f1.z); tmp[7] = f2b(f1.w);
            *(bf8*)&As[r][cg] = *(bf8*)tmp;
        }
#pragma unroll
        for (int p = 0; p < 4; p++) {   // B tile: 256(n) x 64(k)
            int nr = p * 64 + (t >> 3), cg = (t & 7) * 8;
            *(bf8*)&Bs[nr][cg] = *(const bf8*)&WT[(n0 + nr) * 256 + kt * 64 + cg];
        }
        __syncthreads();
#pragma unroll
        for (int c = 0; c < 2; c++) {
            bf8 af = *(bf8*)&As[w * 16 + l15][c * 32 + q4 * 8];
#pragma unroll
            for (int nt = 0; nt < 16; nt++) {
                bf8 bf = *(bf8*)&Bs[nt * 16 + l15][c * 32 + q4 * 8];
                acc[nt] = __builtin_amdgcn_mfma_f32_16x16x32_bf16(af, bf, acc[nt], 0, 0, 0);
            }
        }
    }

    const int rb = m0 + w * 16 + q4 * 4;
    if (blockIdx.y == 0) {
#pragma unroll
        for (int nt = 0; nt < 16; nt++) {
            int col = nt * 16 + l15;
#pragma unroll
            for (int r = 0; r < 4; r++) qo[(rb + r) * 256 + col] = f2b(acc[nt][r]);
        }
    } else if (blockIdx.y == 1) {
#pragma unroll
        for (int nt = 0; nt < 16; nt++) {
            int col = nt * 16 + l15;
#pragma unroll
            for (int r = 0; r < 4; r++) ko[(rb + r) * 256 + col] = f2b(acc[nt][r]);
        }
    } else if (blockIdx.y == 2) {          // v transposed: vT[b][c][n]
        int bb = rb >> 12, nn = rb & 4095;
#pragma unroll
        for (int nt = 0; nt < 16; nt++) {
            int vc = nt * 16 + l15;
            ushort4 pk;
            pk.x = f2b(acc[nt][0]); pk.y = f2b(acc[nt][1]);
            pk.z = f2b(acc[nt][2]); pk.w = f2b(acc[nt][3]);
            *(ushort4*)&vT[(bb * 256 + vc) * 4096 + nn] = pk;
        }
    } else {                               // z = gelu_exact(y + b_gate)
#pragma unroll
        for (int nt = 0; nt < 16; nt++) {
            int gc = nt * 16 + l15;
            float bg = b_gate[gc];
#pragma unroll
            for (int r = 0; r < 4; r++) {
                float v = acc[nt][r] + bg;
                float g = 0.5f * v * (1.0f + erff(v * 0.70710678118654752f));
                zo[(rb + r) * 256 + gc] = f2b(g);
            }
        }
    }
}

// ---------------------------------------------------------------------------
// Kernel 2: depthwise 3x3 conv PE, sliding-window (3 loads/pixel).
// ---------------------------------------------------------------------------
__global__ __launch_bounds__(256) void conv_pe(
        const u16* __restrict__ q, const float* __restrict__ pw,
        const float* __restrict__ pb, u16* __restrict__ pe) {
    const int b = blockIdx.x >> 6, h = blockIdx.x & 63;
    const int c = threadIdx.x;
    float wgt[9];
#pragma unroll
    for (int i = 0; i < 9; i++) wgt[i] = pw[c * 9 + i];
    const float bias = pb[c];
    const u16* qb = q + b * (4096 * 256);
    u16* peb = pe + b * (4096 * 256);
    const bool vTop = h > 0, vBot = h < 63;
    const u16* rT = qb + (h - 1) * 64 * 256 + c;
    const u16* rM = qb + h * 64 * 256 + c;
    const u16* rB = qb + (h + 1) * 64 * 256 + c;

    float t0 = 0.f, t1, t2, m0v = 0.f, m1, m2, b0 = 0.f, b1, b2v;
    t1 = vTop ? b2f(rT[0]) : 0.f;
    m1 = b2f(rM[0]);
    b1 = vBot ? b2f(rB[0]) : 0.f;
    for (int w2 = 0; w2 < 64; ++w2) {
        if (w2 < 63) {
            int o = (w2 + 1) * 256;
            t2 = vTop ? b2f(rT[o]) : 0.f;
            m2 = b2f(rM[o]);
            b2v = vBot ? b2f(rB[o]) : 0.f;
        } else { t2 = 0.f; m2 = 0.f; b2v = 0.f; }
        float acc = bias
            + wgt[0] * t0 + wgt[1] * t1 + wgt[2] * t2
            + wgt[3] * m0v + wgt[4] * m1 + wgt[5] * m2
            + wgt[6] * b0 + wgt[7] * b1 + wgt[8] * b2v;
        peb[(h * 64 + w2) * 256 + c] = f2b(acc);
        t0 = t1; t1 = t2; m0v = m1; m1 = m2; b0 = b1; b1 = b2v;
    }
}

// ---------------------------------------------------------------------------
// Kernel 3: flash attention v8 — 32x32x16 MFMA, P NEVER touches LDS.
// Key identity: S^T C-layout (col=q, row=key) == PV B-operand layout for
// K=16-per-half steps, up to a lane^32 half-exchange (4 shfl_xor/wave/iter).
// Qt=64, Kt=128, iters=32. Grid 256 = 64 qt x 4 batches (b=bid&3).
// 512 thr / 8 waves: (kg=w>>1: key-32 stripe of 128; qh=w&1: q-32 half).
// K (and Q in prologue) via global_load_lds into pair-1040 padded Kst;
// V via regs->ds_write_b128 into 272B-row Vs. All LDS reads/writes are at
// the b128 8-cyc ideal (bank math checked). O = per-wave partial
// [256 vc][32 q] over its key-stripes; kg-tree-reduce via LDS at the end;
// epilogue re-coalesced through an LDS [q][vc] fp32 transpose.
// ---------------------------------------------------------------------------
__global__ __launch_bounds__(512) void attn(
        const u16* __restrict__ q, const u16* __restrict__ k,
        const u16* __restrict__ vT, const u16* __restrict__ pe,
        const u16* __restrict__ z, u16* __restrict__ u) {
    __shared__ __align__(16) char smem[136192];  // Kst 66560 | Vs 69632
    __shared__ float l_part[4][64];
    u16* Kst = (u16*)smem;                 // 128 rows x 512B, pair-1040 layout
    u16* Vs  = (u16*)(smem + 66560);       // 256 rows x (128 keys + 8 pad)

    const int t = threadIdx.x;
    const int w = t >> 6, lane = t & 63;
    const int ln = lane & 31, hh = lane >> 5;
    const int kg = w >> 1, qh = w & 1;
    const int b = blockIdx.x & 3, qt = blockIdx.x >> 2;
    const int m0 = b * 4096 + qt * 64;

    const u16* kb = k + (size_t)b * 4096 * 256;
    const u16* vb = vT + (size_t)b * 256 * 4096;

    // Kst element index for (row, el)
    auto kidx = [&](int row, int el) -> int {
        return (row >> 1) * 520 + (row & 1) * 256 + el;
    };
    // stage `rows` rows (row-major, 512B rows) into Kst via global_load_lds
    auto stageRows = [&](const u16* src, int pairs) {
        for (int rr = 0; rr < pairs / 8; rr++) {
            int p = rr * 8 + w;
            const u16* g = src + (size_t)(2 * p + hh) * 256 + ln * 8;
            u16* l = &Kst[p * 520];
            __builtin_amdgcn_global_load_lds(
                (const __attribute__((address_space(1))) unsigned int*)g,
                (__attribute__((address_space(3))) unsigned int*)l, 16, 0, 0);
        }
    };

    // ---- prologue: stage Q (64 rows) -> qf regs, then K[0], V[0] ----
    stageRows(q + (size_t)m0 * 256, 32);
    __syncthreads();
    bf8 qf[16];
#pragma unroll
    for (int c = 0; c < 16; c++)
        qf[c] = *(bf8*)&Kst[kidx(qh * 32 + ln, c * 16 + hh * 8)];
    __syncthreads();                        // qf read before K overwrites

    stageRows(kb, 64);                      // K[0] (128 rows)
    bf8 vreg[8];
    {
        const int vcb = t >> 4, ch = t & 15;
#pragma unroll
        for (int j = 0; j < 8; j++)
            vreg[j] = *(const bf8*)&vb[(size_t)(j * 32 + vcb) * 4096 + ch * 8];
    }

    f16v O[8];
#pragma unroll
    for (int vt = 0; vt < 8; vt++)
#pragma unroll
        for (int e = 0; e < 16; e++) O[vt][e] = 0.f;
    float lrow = 0.f;

    for (int kt = 0; kt < 32; ++kt) {
        __syncthreads();                    // drains K[kt] DMA + V[kt] loads

        // ---- commit V[kt] -> Vs (272B rows) ----
        {
            const int vcb = t >> 4, ch = t & 15;
#pragma unroll
            for (int j = 0; j < 8; j++)
                *(bf8*)&Vs[(j * 32 + vcb) * 136 + ch * 8] = vreg[j];
        }

        // ---- QK: St = K_stripe · Q^T  (col=q, row=key_local) ----
        f16v St;
#pragma unroll
        for (int e = 0; e < 16; e++) St[e] = 0.f;
#pragma unroll
        for (int c = 0; c < 16; c++) {
            bf8 kf = *(bf8*)&Kst[kidx(kg * 32 + ln, c * 16 + hh * 8)];
            St = __builtin_amdgcn_mfma_f32_32x32x16_bf16(kf, qf[c], St, 0, 0, 0);
        }

        // ---- P = exp(S*scale) in regs; half-exchange -> 2 B-frags ----
        float e_[16];
        float psum = 0.f;
#pragma unroll
        for (int r = 0; r < 16; r++) {
            e_[r] = exp2f(fminf(fmaxf(St[r] * SC_LOG2E, -30.f), 30.f));
            psum += e_[r];
        }
        psum += __shfl_xor(psum, 32);
        lrow += psum;
        uint32_t pk[8];
#pragma unroll
        for (int r2 = 0; r2 < 8; r2++)
            pk[r2] = (uint32_t)f2b(e_[2 * r2]) | ((uint32_t)f2b(e_[2 * r2 + 1]) << 16);
        bf8 pf[2];
#pragma unroll
        for (int s = 0; s < 2; s++) {
            uint32_t s0 = hh ? pk[4 * s] : pk[4 * s + 2];
            uint32_t s1 = hh ? pk[4 * s + 1] : pk[4 * s + 3];
            uint32_t r0 = (uint32_t)__shfl_xor((int)s0, 32);
            uint32_t r1 = (uint32_t)__shfl_xor((int)s1, 32);
            union { uint32_t d[4]; bf8 v; } cv;
            cv.d[0] = hh ? r0 : pk[4 * s];
            cv.d[1] = hh ? r1 : pk[4 * s + 1];
            cv.d[2] = hh ? pk[4 * s + 2] : r0;
            cv.d[3] = hh ? pk[4 * s + 3] : r1;
            pf[s] = cv.v;
        }
        __syncthreads();                    // Vs visible; Kst reads done

        // ---- prefetch next tile (flies across PV, drains at top barrier) --
        if (kt < 31) {
            stageRows(kb + (size_t)(kt + 1) * 128 * 256, 64);
            const int vcb = t >> 4, ch = t & 15;
#pragma unroll
            for (int j = 0; j < 8; j++)
                vreg[j] = *(const bf8*)&vb[(size_t)(j * 32 + vcb) * 4096
                                           + (kt + 1) * 128 + ch * 8];
        }

        // ---- PV: O[vt] += V^T_chunk · P  (A from Vs, B = pf regs) ----
#pragma unroll
        for (int vt = 0; vt < 8; vt++) {
            bf8 v0 = *(bf8*)&Vs[(vt * 32 + ln) * 136 + kg * 32 + hh * 8];
            bf8 v1 = *(bf8*)&Vs[(vt * 32 + ln) * 136 + kg * 32 + 16 + hh * 8];
            O[vt] = __builtin_amdgcn_mfma_f32_32x32x16_bf16(v0, pf[0], O[vt], 0, 0, 0);
            O[vt] = __builtin_amdgcn_mfma_f32_32x32x16_bf16(v1, pf[1], O[vt], 0, 0, 0);
        }
    }

    if (hh == 0) l_part[kg][qh * 32 + ln] = lrow;
    __syncthreads();

    // ---- kg-tree reduction of O partials through LDS ----
    float* buf = (float*)smem;
    if (kg >= 2) {                          // round 1: kg 2,3 write all 8 vt
        float* dst = buf + ((kg - 2) * 2 + qh) * 8192;
#pragma unroll
        for (int vt = 0; vt < 8; vt++)
#pragma unroll
            for (int r = 0; r < 16; r++)
                dst[vt * 1024 + r * 64 + lane] = O[vt][r];
    }
    __syncthreads();
    if (kg < 2) {
        const float* src = buf + (kg * 2 + qh) * 8192;
#pragma unroll
        for (int vt = 0; vt < 8; vt++)
#pragma unroll
            for (int r = 0; r < 16; r++)
                O[vt][r] += src[vt * 1024 + r * 64 + lane];
    }
    __syncthreads();
    if (kg < 2) {                           // round 2: exchange halves
        float* dst = buf + (qh * 2 + kg) * 4096;
        int vtb = (kg == 0) ? 4 : 0;
#pragma unroll
        for (int v2 = 0; v2 < 4; v2++)
#pragma unroll
            for (int r = 0; r < 16; r++)
                dst[v2 * 1024 + r * 64 + lane] = O[vtb + v2][r];
    }
    __syncthreads();
    if (kg < 2) {
        const float* src = buf + (qh * 2 + (1 - kg)) * 4096;
        int vtb = (kg == 0) ? 0 : 4;
#pragma unroll
        for (int v2 = 0; v2 < 4; v2++)
#pragma unroll
            for (int r = 0; r < 16; r++)
                O[vtb + v2][r] += src[v2 * 1024 + r * 64 + lane];
    }
    __syncthreads();

    // ---- finalize O/l -> LDS [q][264] fp32 transpose ----
    float* ob = (float*)smem;               // 64 x 264 floats
    if (kg < 2) {
        const int qq = qh * 32 + ln;
        float lt = l_part[0][qq] + l_part[1][qq] + l_part[2][qq] + l_part[3][qq];
        float linv = 1.0f / lt;
#pragma unroll
        for (int v2 = 0; v2 < 4; v2++) {
            int vt = kg * 4 + v2;
#pragma unroll
            for (int r2 = 0; r2 < 4; r2++) {
                f4 c;
                c[0] = O[vt][r2 * 4 + 0] * linv;
                c[1] = O[vt][r2 * 4 + 1] * linv;
                c[2] = O[vt][r2 * 4 + 2] * linv;
                c[3] = O[vt][r2 * 4 + 3] * linv;
                *(f4*)&ob[qq * 264 + vt * 32 + r2 * 8 + 4 * hh] = c;
            }
        }
    }
    __syncthreads();

    // ---- coalesced epilogue: u = (O + pe) * z ----
    const int L = t & 31;
#pragma unroll
    for (int mm = 0; mm < 4; mm++) {
        int m = mm * 16 + (t >> 5);
        f4 a0 = *(f4*)&ob[m * 264 + L * 8];
        f4 a1 = *(f4*)&ob[m * 264 + L * 8 + 4];
        size_t base = (size_t)(m0 + m) * 256 + L * 8;
        ushort4 p0 = *(const ushort4*)&pe[base];
        ushort4 p1 = *(const ushort4*)&pe[base + 4];
        ushort4 z0 = *(const ushort4*)&z[base];
        ushort4 z1 = *(const ushort4*)&z[base + 4];
        ushort4 o0, o1;
        o0.x = f2b((a0[0] + b2f(p0.x)) * b2f(z0.x));
        o0.y = f2b((a0[1] + b2f(p0.y)) * b2f(z0.y));
        o0.z = f2b((a0[2] + b2f(p0.z)) * b2f(z0.z));
        o0.w = f2b((a0[3] + b2f(p0.w)) * b2f(z0.w));
        o1.x = f2b((a1[0] + b2f(p1.x)) * b2f(z1.x));
        o1.y = f2b((a1[1] + b2f(p1.y)) * b2f(z1.y));
        o1.z = f2b((a1[2] + b2f(p1.z)) * b2f(z1.z));
        o1.w = f2b((a1[3] + b2f(p1.w)) * b2f(z1.w));
        *(ushort4*)&u[base] = o0;
        *(ushort4*)&u[base + 4] = o1;
    }
}

// ---------------------------------------------------------------------------
// Kernel 4: out = u @ W_proj   (M=16384, N=256, K=256). f32 output.
// ---------------------------------------------------------------------------
__global__ __launch_bounds__(256) void gemm_proj(
        const u16* __restrict__ u, const u16* __restrict__ WTp,
        float* __restrict__ out) {
    __shared__ u16 As[64][72];
    __shared__ u16 Bs[256][72];
    const int t = threadIdx.x;
    const int w = t >> 6, lane = t & 63, l15 = lane & 15, q4 = lane >> 4;
    const int m0 = blockIdx.x * 64;

    f4 acc[16];
#pragma unroll
    for (int i = 0; i < 16; i++) acc[i] = (f4){0.f, 0.f, 0.f, 0.f};

    for (int kt = 0; kt < 4; ++kt) {
        __syncthreads();
#pragma unroll
        for (int p = 0; p < 2; p++) {
            int r = p * 32 + (t >> 3), cg = (t & 7) * 8;
            *(bf8*)&As[r][cg] = *(const bf8*)&u[(m0 + r) * 256 + kt * 64 + cg];
        }
#pragma unroll
        for (int p = 0; p < 8; p++) {
            int nr = p * 32 + (t >> 3), cg = (t & 7) * 8;
            *(bf8*)&Bs[nr][cg] = *(const bf8*)&WTp[nr * 256 + kt * 64 + cg];
        }
        __syncthreads();
#pragma unroll
        for (int c = 0; c < 2; c++) {
            bf8 af = *(bf8*)&As[w * 16 + l15][c * 32 + q4 * 8];
#pragma unroll
            for (int nt = 0; nt < 16; nt++) {
                bf8 bf = *(bf8*)&Bs[nt * 16 + l15][c * 32 + q4 * 8];
                acc[nt] = __builtin_amdgcn_mfma_f32_16x16x32_bf16(af, bf, acc[nt], 0, 0, 0);
            }
        }
    }
    const int rb = m0 + w * 16 + q4 * 4;
#pragma unroll
    for (int nt = 0; nt < 16; nt++) {
        int col = nt * 16 + l15;
#pragma unroll
        for (int r = 0; r < 4; r++) out[(rb + r) * 256 + col] = acc[nt][r];
    }
}

// ---------------------------------------------------------------------------
extern "C" void kernel_launch(void* const* d_in, const int* in_sizes, int n_in,
                              void* d_out, int out_size, void* d_ws, size_t ws_size,
                              hipStream_t stream) {
    (void)in_sizes; (void)n_in; (void)out_size; (void)ws_size;
    const float* x      = (const float*)d_in[0];
    const float* Wqkv   = (const float*)d_in[1];
    const float* Wgate  = (const float*)d_in[2];
    const float* bgate  = (const float*)d_in[3];
    const float* Wproj  = (const float*)d_in[4];
    const float* pw     = (const float*)d_in[5];
    const float* pb     = (const float*)d_in[6];
    float* out = (float*)d_out;

    char* ws = (char*)d_ws;
    u16* WT_all = (u16*)(ws);                   // 524288 B
    u16* WTp    = (u16*)(ws + 524288);          // 131072 B
    u16* q      = (u16*)(ws + 655360);          // 8388608
    u16* k      = (u16*)(ws + 9043968);         // 8388608
    u16* vT     = (u16*)(ws + 17432576);        // 8388608
    u16* z      = (u16*)(ws + 25821184);        // 8388608
    u16* pe     = (u16*)(ws + 34209792);        // 8388608
    u16* u      = (u16*)(ws + 42598400);        // 8388608

    prep_weights<<<1280, 256, 0, stream>>>(Wqkv, Wgate, Wproj, WT_all, WTp);
    gemm_qkvz<<<dim3(128, 4), 512, 0, stream>>>(x, WT_all, bgate, q, k, vT, z);
    conv_pe<<<256, 256, 0, stream>>>(q, pw, pb, pe);
    attn<<<256, 512, 0, stream>>>(q, k, vT, pe, z, u);
    gemm_proj<<<256, 256, 0, stream>>>(u, WTp, out);
}